// Round 1
// baseline (330.663 us; speedup 1.0000x reference)
//
#include <hip/hip_runtime.h>
#include <hip/hip_cooperative_groups.h>
#include <math.h>

#define D_DIM 2048
#define M_EV  16384
#define LCH   32
#define CCH   (M_EV / LCH)      // 512 chunks
#define SEG   32                // chunks per scan segment
#define NSEG  (CCH / SEG)       // 16 segments
#define BETA  1.0f

#define NBLK  CCH               // 512 blocks; one chunk per block in P3
#define NTHR  256               // 4 waves per block
#define TOTTHR (NBLK * NTHR)    // 131072 threads

namespace cg = cooperative_groups;

__device__ __forceinline__ float softplus_f(float x){
  float e = __expf(-fabsf(x));
  return fmaxf(x, 0.0f) + __logf(1.0f + e);
}

// float -> bf16 (RNE); inputs are finite non-negative here.
__device__ __forceinline__ unsigned short f2bf(float f){
  unsigned b = __float_as_uint(f);
  return (unsigned short)((b + 0x7FFFu + ((b >> 16) & 1u)) >> 16);
}
__device__ __forceinline__ float bf2f(unsigned short u){
  return __uint_as_float(((unsigned)u) << 16);
}

// T_max arrives as a 1-element array; decode int-vs-float defensively.
__device__ __forceinline__ float decode_T(const void* p){
  unsigned bits = *(const unsigned*)p;
  float fv = __uint_as_float(bits);
  return (fv >= 1e-3f && fv <= 1e7f) ? fv : (float)(int)bits;
}

__device__ __forceinline__ float wave_red(float v){
  #pragma unroll
  for (int o = 32; o > 0; o >>= 1) v += __shfl_down(v, o);
  return v;
}

// Single cooperative kernel: P0 zero | P1 small+scatter | P2 alpha+scan | P3 events.
// Same math/layout as the 4-dispatch version; grid.sync() replaces kernel boundaries.
__global__ __launch_bounds__(NTHR, 2) void k_fused(
    const float* __restrict__ t, const int* __restrict__ m,
    const void* Tp, const float* __restrict__ log_mu,
    const float* __restrict__ la,
    float* __restrict__ muw, float* __restrict__ contrib,
    float* __restrict__ SL, float* __restrict__ dchunk,
    float* __restrict__ cumdec, float* __restrict__ Aseg,
    float* __restrict__ Carry, unsigned short* __restrict__ sA,
    float* __restrict__ acc, float* __restrict__ out)
{
  cg::grid_group grid = cg::this_grid();
  const int b   = blockIdx.x;
  const int tid = threadIdx.x;
  const int gtid = b * NTHR + tid;

  // ---------------- P0: zero SL (4 MB), contrib, acc (replaces hipMemsetAsync)
  {
    const float4 z = make_float4(0.f, 0.f, 0.f, 0.f);
    float4* SL4 = (float4*)SL;
    SL4[gtid] = z;                       // 2 * 131072 float4 = 1,048,576 floats
    SL4[gtid + TOTTHR] = z;
    if (gtid < D_DIM / 4) ((float4*)contrib)[gtid] = z;
    if (gtid < 16) acc[gtid] = 0.f;
  }
  grid.sync();

  // ---------------- P1: muw | event scatter (contrib + SL) | chunk decays | Aseg
  if (gtid < 2048){
    float v = softplus_f(log_mu[gtid]) + 1e-6f;
    muw[gtid] = v;
    float s = wave_red(v);
    if ((tid & 63) == 0) atomicAdd(&acc[2], s);
  } else if (gtid < 2048 + M_EV){
    int i = gtid - 2048;
    int d = m[i];
    float ti = t[i];
    float T = decode_T(Tp);
    atomicAdd(&contrib[d], 1.0f - __expf(-BETA * (T - ti)));
    int c = i >> 5;
    if (c < CCH - 1){                    // last chunk's carry is unused
      float tn = t[(c+1)*LCH];
      atomicAdd(&SL[(size_t)c * D_DIM + d], __expf(-BETA * (tn - ti)));
    }
  } else if (gtid < 2048 + M_EV + CCH){
    int c = gtid - (2048 + M_EV);        // c in [0,512)
    float tc = t[c*LCH];
    dchunk[c] = (c < CCH-1) ? __expf(-BETA * (t[(c+1)*LCH] - tc)) : 1.0f;
    int s0c = (c >> 5) << 5;             // segment-start chunk
    cumdec[c] = __expf(-BETA * (tc - t[s0c*LCH]));
  } else if (gtid < 2048 + M_EV + CCH + NSEG){
    int s = gtid - (2048 + M_EV + CCH);
    Aseg[s] = (s < NSEG-1)
      ? __expf(-BETA * (t[(s+1)*SEG*LCH] - t[s*SEG*LCH])) : 1.0f;
  }
  grid.sync();

  // ---------------- P2a: sA = bf16(softplus(log_alpha)) + integral partial acc[1]
  {
    const float4* la4 = (const float4*)la;
    ushort4* sA4 = (ushort4*)sA;
    float p = 0.f;
    #pragma unroll
    for (int u = 0; u < 8; ++u){
      int i4 = gtid + u * TOTTHR;
      float4 x = la4[i4];
      float4 sp;
      sp.x = softplus_f(x.x); sp.y = softplus_f(x.y);
      sp.z = softplus_f(x.z); sp.w = softplus_f(x.w);
      ushort4 h;
      h.x = f2bf(sp.x); h.y = f2bf(sp.y); h.z = f2bf(sp.z); h.w = f2bf(sp.w);
      sA4[i4] = h;
      int col = (i4 * 4) & (D_DIM - 1);
      p = fmaf(sp.x, contrib[col+0], p);
      p = fmaf(sp.y, contrib[col+1], p);
      p = fmaf(sp.z, contrib[col+2], p);
      p = fmaf(sp.w, contrib[col+3], p);
    }
    __shared__ float red[4];
    float wsum = wave_red(p);
    int lane = tid & 63, wid = tid >> 6;
    if (lane == 0) red[wid] = wsum;
    __syncthreads();
    if (tid == 0) atomicAdd(&acc[1], red[0]+red[1]+red[2]+red[3]);
  }

  // ---------------- P2b: per-segment local exclusive scan of SL + Carry
  if (gtid < NSEG * D_DIM){              // 32768 column-segments
    const int seg = gtid >> 11;          // / 2048
    const int j   = gtid & (D_DIM - 1);
    const int c0  = seg * SEG;
    const size_t base = (size_t)c0 * D_DIM + j;
    float u2 = 0.f;
    float cur[4], nxt[4];
    #pragma unroll
    for (int q = 0; q < 4; ++q) cur[q] = SL[base + (size_t)q * D_DIM];
    for (int g = 0; g < SEG; g += 4){
      #pragma unroll
      for (int q = 0; q < 4; ++q)
        nxt[q] = (g+4 < SEG) ? SL[base + (size_t)(g+4+q) * D_DIM] : 0.f;
      #pragma unroll
      for (int q = 0; q < 4; ++q){
        int c = c0 + g + q;
        float l = cur[q];
        SL[(size_t)c * D_DIM + j] = u2;
        u2 = fmaf(dchunk[c], u2, l);
      }
      #pragma unroll
      for (int q = 0; q < 4; ++q) cur[q] = nxt[q];
    }
    Carry[(size_t)seg * D_DIM + j] = u2;
  }
  grid.sync();

  // ---------------- P3: per-chunk event log-intensities (one chunk per block)
  {
    __shared__ float S0[D_DIM];
    __shared__ float tl[LCH];
    __shared__ int   ml[LCH];
    __shared__ float wred[4];
    const int c = b;
    const int seg = c >> 5;
    const float cd = cumdec[c];
    {
      const size_t rowc = (size_t)c * D_DIM;
      const int col = tid * 4;           // two float4 per thread: col, col+1024
      float4 sv0 = *(const float4*)(SL + rowc + col);
      float4 sv1 = *(const float4*)(SL + rowc + 1024 + col);
      float4 e0 = make_float4(0,0,0,0), e1 = make_float4(0,0,0,0);
      float wgt = 1.f;
      for (int s = seg - 1; s >= 0; --s){
        const float4 cr0 = *(const float4*)(Carry + (size_t)s * D_DIM + col);
        const float4 cr1 = *(const float4*)(Carry + (size_t)s * D_DIM + 1024 + col);
        e0.x = fmaf(cr0.x, wgt, e0.x); e0.y = fmaf(cr0.y, wgt, e0.y);
        e0.z = fmaf(cr0.z, wgt, e0.z); e0.w = fmaf(cr0.w, wgt, e0.w);
        e1.x = fmaf(cr1.x, wgt, e1.x); e1.y = fmaf(cr1.y, wgt, e1.y);
        e1.z = fmaf(cr1.z, wgt, e1.z); e1.w = fmaf(cr1.w, wgt, e1.w);
        wgt *= Aseg[s];
      }
      float4 o0, o1;
      o0.x = fmaf(e0.x, cd, sv0.x); o0.y = fmaf(e0.y, cd, sv0.y);
      o0.z = fmaf(e0.z, cd, sv0.z); o0.w = fmaf(e0.w, cd, sv0.w);
      o1.x = fmaf(e1.x, cd, sv1.x); o1.y = fmaf(e1.y, cd, sv1.y);
      o1.z = fmaf(e1.z, cd, sv1.z); o1.w = fmaf(e1.w, cd, sv1.w);
      *(float4*)&S0[col]        = o0;
      *(float4*)&S0[1024 + col] = o1;
    }
    if (tid < LCH){
      ml[tid] = m[c*LCH + tid];
      tl[tid] = t[c*LCH + tid];
    }
    __syncthreads();

    const int l = tid & 63, w = tid >> 6;   // 4 waves, 8 events each
    const int l4 = l * 4;

    float4 s0[8];
    #pragma unroll
    for (int u = 0; u < 8; ++u) s0[u] = *(const float4*)&S0[u*256 + l4];

    const float t0 = tl[0];
    float lgw = 0.f;
    #pragma unroll
    for (int q = 0; q < 8; ++q){
      const int k = w*8 + q;
      const int d = ml[k];
      const unsigned short* row = sA + (size_t)d * D_DIM;
      float p = 0.f;
      #pragma unroll
      for (int u = 0; u < 8; ++u){
        ushort4 a = *(const ushort4*)(row + u*256 + l4);
        p = fmaf(bf2f(a.x), s0[u].x, p);
        p = fmaf(bf2f(a.y), s0[u].y, p);
        p = fmaf(bf2f(a.z), s0[u].z, p);
        p = fmaf(bf2f(a.w), s0[u].w, p);
      }
      const float tk = tl[k];
      float g = 0.f;
      if (l < k) g = bf2f(row[ml[l]]) * __expf(tl[l] - tk);  // exact pair term
      p = fmaf(p, __expf(t0 - tk), g);
      float v = wave_red(p);
      if (l == 0) lgw += __logf(muw[d] + v + 1e-8f);
    }
    if (l == 0) wred[w] = lgw;
    __syncthreads();
    if (tid == 0){
      float lg = (wred[0]+wred[1]) + (wred[2]+wred[3]);
      atomicAdd(&acc[0], lg);
    }
  }
  grid.sync();

  // ---------------- finalize
  if (gtid == 0){
    float a0 = atomicAdd(&acc[0], 0.0f);   // device-scope reads
    float a1 = atomicAdd(&acc[1], 0.0f);
    float a2 = atomicAdd(&acc[2], 0.0f);
    float T = decode_T(Tp);
    out[0] = a0 - (T * a2 + a1 * (1.0f / BETA));
  }
}

extern "C" void kernel_launch(void* const* d_in, const int* in_sizes, int n_in,
                              void* d_out, int out_size, void* d_ws, size_t ws_size,
                              hipStream_t stream) {
  const float* t_events  = (const float*)d_in[0];
  const int*   marks     = (const int*)  d_in[1];
  const void*  Tp        =               d_in[2];
  const float* log_mu    = (const float*)d_in[3];
  const float* log_alpha = (const float*)d_in[4];
  float* out = (float*)d_out;

  // ws layout (floats), same as before:
  // SL[CCH*D] | contrib[D] | acc[16] | Carry[NSEG*D] | muw[D]
  //   | dchunk[CCH] | cumdec[CCH] | Aseg[NSEG] | sA[D*D bf16]
  float* ws      = (float*)d_ws;
  float* SL      = ws;
  float* contrib = SL + (size_t)CCH * D_DIM;
  float* acc     = contrib + D_DIM;
  float* Carry   = acc + 16;
  float* muw     = Carry + (size_t)NSEG * D_DIM;
  float* dchunk  = muw + D_DIM;
  float* cumdec  = dchunk + CCH;
  float* Aseg    = cumdec + CCH;
  unsigned short* sA = (unsigned short*)(Aseg + NSEG);   // 16B-aligned offset

  void* args[] = {
    (void*)&t_events, (void*)&marks, (void*)&Tp, (void*)&log_mu,
    (void*)&log_alpha, (void*)&muw, (void*)&contrib, (void*)&SL,
    (void*)&dchunk, (void*)&cumdec, (void*)&Aseg, (void*)&Carry,
    (void*)&sA, (void*)&acc, (void*)&out
  };
  hipLaunchCooperativeKernel((const void*)k_fused, dim3(NBLK), dim3(NTHR),
                             args, 0, stream);
}

// Round 2
// 131.767 us; speedup vs baseline: 2.5094x; 2.5094x over previous
//
#include <hip/hip_runtime.h>
#include <math.h>

#define D_DIM 2048
#define M_EV  16384
#define LCH   32
#define CCH   (M_EV / LCH)      // 512 chunks
#define SEG   32                // chunks per scan segment
#define NSEG  (CCH / SEG)       // 16 segments
#define BETA  1.0f
#define NSH   8                 // colsum shards

__device__ __forceinline__ float softplus_f(float x){
  float e = __expf(-fabsf(x));
  return fmaxf(x, 0.0f) + __logf(1.0f + e);
}

// float -> bf16 (RNE); inputs are finite non-negative here.
__device__ __forceinline__ unsigned short f2bf(float f){
  unsigned b = __float_as_uint(f);
  return (unsigned short)((b + 0x7FFFu + ((b >> 16) & 1u)) >> 16);
}
__device__ __forceinline__ float bf2f(unsigned short u){
  return __uint_as_float(((unsigned)u) << 16);
}

// T_max arrives as a 1-element array; decode int-vs-float defensively.
__device__ __forceinline__ float decode_T(const void* p){
  unsigned bits = *(const unsigned*)p;
  float fv = __uint_as_float(bits);
  return (fv >= 1e-3f && fv <= 1e7f) ? fv : (float)(int)bits;
}

__device__ __forceinline__ float wave_red(float v){
  #pragma unroll
  for (int o = 32; o > 0; o >>= 1) v += __shfl_down(v, o);
  return v;
}

// k_prep: NO pre-zeroed memory needed anywhere.
//   [0,8)   : muw[j] = softplus(log_mu)+eps ; per-block partial -> acc[8+b]
//   [8,72)  : 256 events = 8 chunks/block. Zero 64KB LDS tile, LDS-atomic
//             scatter SL contributions, stream tile to global (coalesced).
//   [72,74) : dchunk/cumdec per chunk; Aseg (block 72); zero colsum shards;
//             zero acc[0..3] (block 73).
__global__ __launch_bounds__(256) void k_prep(
    const float* __restrict__ t, const int* __restrict__ m,
    const float* __restrict__ log_mu,
    float* __restrict__ muw, float* __restrict__ SL,
    float* __restrict__ dchunk, float* __restrict__ cumdec,
    float* __restrict__ Aseg, float* __restrict__ colsum,
    float* __restrict__ acc)
{
  __shared__ float Srow[8 * D_DIM];     // 64 KB
  const int b = blockIdx.x, tid = threadIdx.x;
  if (b < 8){
    int j = b*256 + tid;
    float v = softplus_f(log_mu[j]) + 1e-6f;
    muw[j] = v;
    float s = wave_red(v);
    if ((tid & 63) == 0) Srow[tid >> 6] = s;
    __syncthreads();
    if (tid == 0) acc[8 + b] = (Srow[0]+Srow[1]) + (Srow[2]+Srow[3]);
  } else if (b < 72){
    float4* S4 = (float4*)Srow;
    const float4 z = make_float4(0.f,0.f,0.f,0.f);
    #pragma unroll
    for (int k = 0; k < 16; ++k) S4[k*256 + tid] = z;
    __syncthreads();
    const int i = (b-8)*256 + tid;
    const int c = i >> 5;                       // global chunk of this event
    if (c < CCH - 1){                           // last chunk's carry unused
      float tn = t[(c+1)*LCH];
      atomicAdd(&Srow[(tid >> 5)*D_DIM + m[i]], __expf(-BETA * (tn - t[i])));
    }
    __syncthreads();
    float4* G4 = (float4*)(SL + (size_t)(b-8) * (8*D_DIM));
    #pragma unroll
    for (int k = 0; k < 16; ++k) G4[k*256 + tid] = S4[k*256 + tid];
  } else {
    int c = (b-72)*256 + tid;                   // c in [0,512)
    float tc = t[c*LCH];
    dchunk[c] = (c < CCH-1) ? __expf(-BETA * (t[(c+1)*LCH] - tc)) : 1.0f;
    int s0c = (c >> 5) << 5;                    // segment-start chunk
    cumdec[c] = __expf(-BETA * (tc - t[s0c*LCH]));
    // zero colsum shards: 16384 floats over 512 threads -> 8 float4 each
    float4* C4 = (float4*)colsum;
    const float4 z = make_float4(0.f,0.f,0.f,0.f);
    int q0 = ((b-72)*256 + tid) * 8;
    #pragma unroll
    for (int k = 0; k < 8; ++k) C4[q0 + k] = z;
    if (b == 72 && tid < NSEG){
      int s = tid;
      Aseg[s] = (s < NSEG-1)
        ? __expf(-BETA * (t[(s+1)*SEG*LCH] - t[s*SEG*LCH])) : 1.0f;
    }
    if (b == 73 && tid < 4) acc[tid] = 0.f;     // loglik, integral, -, ticket
  }
}

// k_scan_alpha: blocks [0,128) = per-segment local exclusive scan of SL
// (in-place, carry-out per segment); blocks [128,640) = sA =
// bf16(softplus(log_alpha)) + sharded column-sum partials (for the integral).
__global__ __launch_bounds__(256) void k_scan_alpha(
    float* __restrict__ SL, const float* __restrict__ dchunk,
    float* __restrict__ Carry, const float* __restrict__ la,
    unsigned short* __restrict__ sA, float* __restrict__ colsum)
{
  const int b = blockIdx.x, tid = threadIdx.x;
  if (b < 128){
    const int seg = b >> 3, jb = b & 7;
    const int j = jb*256 + tid;
    const int c0 = seg * SEG;
    const size_t base = (size_t)c0 * D_DIM + j;
    float u = 0.f;
    float cur[4], nxt[4];
    #pragma unroll
    for (int q = 0; q < 4; ++q) cur[q] = SL[base + (size_t)q * D_DIM];
    for (int g = 0; g < SEG; g += 4){
      #pragma unroll
      for (int q = 0; q < 4; ++q)
        nxt[q] = (g+4 < SEG) ? SL[base + (size_t)(g+4+q) * D_DIM] : 0.f;
      #pragma unroll
      for (int q = 0; q < 4; ++q){
        int c = c0 + g + q;
        float l = cur[q];
        SL[(size_t)c * D_DIM + j] = u;
        u = fmaf(dchunk[c], u, l);
      }
      #pragma unroll
      for (int q = 0; q < 4; ++q) cur[q] = nxt[q];
    }
    Carry[(size_t)seg * D_DIM + j] = u;
    return;
  }
  const int nthreads = 512*256;               // alpha-range threads
  int atid = (b-128)*256 + tid;
  const float4* la4 = (const float4*)la;
  ushort4* sA4 = (ushort4*)sA;
  float p0=0.f, p1=0.f, p2=0.f, p3=0.f;
  #pragma unroll
  for (int u = 0; u < 8; ++u){
    int i4 = atid + u * nthreads;             // stride ≡ 0 mod row -> same cols
    float4 x = la4[i4];
    float4 sp;
    sp.x = softplus_f(x.x); sp.y = softplus_f(x.y);
    sp.z = softplus_f(x.z); sp.w = softplus_f(x.w);
    ushort4 h;
    h.x = f2bf(sp.x); h.y = f2bf(sp.y); h.z = f2bf(sp.z); h.w = f2bf(sp.w);
    sA4[i4] = h;
    p0 += sp.x; p1 += sp.y; p2 += sp.z; p3 += sp.w;
  }
  const int col = (atid * 4) & (D_DIM - 1);
  float* cs = colsum + (size_t)(b & 7) * D_DIM;   // shard: 32 senders/address
  atomicAdd(&cs[col+0], p0);
  atomicAdd(&cs[col+1], p1);
  atomicAdd(&cs[col+2], p2);
  atomicAdd(&cs[col+3], p3);
}

// k_events: one block (512 thr = 8 waves) per chunk. Decomposed (no seq S):
//   lam_k = mu[d_k] + e^{-(t_k-t0)} * (sA[d_k] . S0)
//                   + sum_{i<k} e^{-(t_k-t_i)} * sA[d_k][m_i]
// E[seg] folded on the fly from Carry/Aseg (backward weights). Also folds the
// per-event integral term colsum[m_k]*(1-exp(-(T-t_k))) into acc[1].
__global__ __launch_bounds__(512) void k_events(
    const float* __restrict__ t, const int* __restrict__ m,
    const unsigned short* __restrict__ sA, const float* __restrict__ muw,
    const float* __restrict__ SL, const float* __restrict__ Carry,
    const float* __restrict__ Aseg, const float* __restrict__ cumdec,
    const float* __restrict__ colsum, float* __restrict__ acc,
    const void* Tp, float* __restrict__ out){
  __shared__ float S0[D_DIM];
  __shared__ float tl[LCH];
  __shared__ int   ml[LCH];
  __shared__ float wred[8];
  const int tid = threadIdx.x;          // 0..511
  const int c = blockIdx.x;
  const int seg = c >> 5;
  const float cd = cumdec[c];

  {
    const float4 sv = *(const float4*)(SL + (size_t)c * D_DIM + tid*4);
    float4 e = {0.f, 0.f, 0.f, 0.f};
    float wgt = 1.f;
    for (int s = seg - 1; s >= 0; --s){
      const float4 cr = *(const float4*)(Carry + (size_t)s * D_DIM + tid*4);
      e.x = fmaf(cr.x, wgt, e.x); e.y = fmaf(cr.y, wgt, e.y);
      e.z = fmaf(cr.z, wgt, e.z); e.w = fmaf(cr.w, wgt, e.w);
      wgt *= Aseg[s];
    }
    float4 s;
    s.x = fmaf(e.x, cd, sv.x); s.y = fmaf(e.y, cd, sv.y);
    s.z = fmaf(e.z, cd, sv.z); s.w = fmaf(e.w, cd, sv.w);
    *(float4*)&S0[tid*4] = s;
  }
  if (tid < LCH){
    ml[tid] = m[c*LCH + tid];
    tl[tid] = t[c*LCH + tid];
  }
  __syncthreads();

  // integral partial: sum_k colsum[m_k]*(1-exp(-(T-t_k))) (wave 0 only)
  if (tid < 64){
    float v = 0.f;
    if (tid < 32){
      int d = ml[tid];
      float cstot = 0.f;
      #pragma unroll
      for (int s = 0; s < NSH; ++s) cstot += colsum[s*D_DIM + d];
      float T = decode_T(Tp);
      v = cstot * (1.0f - __expf(-BETA * (T - tl[tid])));
    }
    v = wave_red(v);
    if (tid == 0) atomicAdd(&acc[1], v);
  }

  const int l = tid & 63, w = tid >> 6;
  const int l4 = l * 4;

  // lane's 32 S0 columns -> registers (one-time)
  float4 s0[8];
  #pragma unroll
  for (int u = 0; u < 8; ++u) s0[u] = *(const float4*)&S0[u*256 + l4];

  const float t0 = tl[0];
  float lgw = 0.f;
  #pragma unroll
  for (int q = 0; q < 4; ++q){
    const int k = w*4 + q;
    const int d = ml[k];
    const unsigned short* row = sA + (size_t)d * D_DIM;
    float p = 0.f;
    #pragma unroll
    for (int u = 0; u < 8; ++u){
      ushort4 a = *(const ushort4*)(row + u*256 + l4);
      p = fmaf(bf2f(a.x), s0[u].x, p);
      p = fmaf(bf2f(a.y), s0[u].y, p);
      p = fmaf(bf2f(a.z), s0[u].z, p);
      p = fmaf(bf2f(a.w), s0[u].w, p);
    }
    const float tk = tl[k];
    float g = 0.f;
    if (l < k) g = bf2f(row[ml[l]]) * __expf(tl[l] - tk);  // exact pair term
    p = fmaf(p, __expf(t0 - tk), g);
    float v = wave_red(p);
    if (l == 0) lgw += __logf(muw[d] + v + 1e-8f);
  }
  if (l == 0) wred[w] = lgw;
  __syncthreads();
  if (tid == 0){
    float lg = ((wred[0]+wred[1])+(wred[2]+wred[3]))
             + ((wred[4]+wred[5])+(wred[6]+wred[7]));
    atomicAdd(&acc[0], lg);
    __threadfence();                        // publish before taking ticket
    unsigned old = atomicAdd((unsigned*)&acc[3], 1u);
    if (old == CCH - 1){                    // last block: finalize
      float a0 = atomicAdd(&acc[0], 0.0f);  // device-scope reads
      float a1 = atomicAdd(&acc[1], 0.0f);
      float musum = 0.f;
      #pragma unroll
      for (int j = 8; j < 16; ++j) musum += atomicAdd(&acc[j], 0.0f);
      float T = decode_T(Tp);
      out[0] = a0 - (T * musum + a1 * (1.0f / BETA));
    }
  }
}

extern "C" void kernel_launch(void* const* d_in, const int* in_sizes, int n_in,
                              void* d_out, int out_size, void* d_ws, size_t ws_size,
                              hipStream_t stream) {
  const float* t_events  = (const float*)d_in[0];
  const int*   marks     = (const int*)  d_in[1];
  const void*  Tp        =               d_in[2];
  const float* log_mu    = (const float*)d_in[3];
  const float* log_alpha = (const float*)d_in[4];
  float* out = (float*)d_out;

  // ws layout (floats) — nothing requires pre-zeroing:
  // SL[CCH*D] | Carry[NSEG*D] | muw[D] | dchunk[CCH] | cumdec[CCH]
  //   | Aseg[NSEG] | colsum[NSH*D] | acc[16] | sA[D*D bf16]
  float* ws      = (float*)d_ws;
  float* SL      = ws;
  float* Carry   = SL + (size_t)CCH * D_DIM;
  float* muw     = Carry + (size_t)NSEG * D_DIM;
  float* dchunk  = muw + D_DIM;
  float* cumdec  = dchunk + CCH;
  float* Aseg    = cumdec + CCH;
  float* colsum  = Aseg + NSEG;
  float* acc     = colsum + (size_t)NSH * D_DIM;
  unsigned short* sA = (unsigned short*)(acc + 16);   // 16B-aligned offset

  k_prep      <<<74, 256, 0, stream>>>(t_events, marks, log_mu, muw, SL,
                                       dchunk, cumdec, Aseg, colsum, acc);
  k_scan_alpha<<<640, 256, 0, stream>>>(SL, dchunk, Carry, log_alpha, sA, colsum);
  k_events    <<<CCH, 512, 0, stream>>>(t_events, marks, sA, muw, SL, Carry,
                                        Aseg, cumdec, colsum, acc, Tp, out);
}

// Round 3
// 112.472 us; speedup vs baseline: 2.9400x; 1.1716x over previous
//
#include <hip/hip_runtime.h>
#include <math.h>

#define D_DIM 2048
#define M_EV  16384
#define LCH   32
#define CCH   (M_EV / LCH)      // 512 chunks
#define SEG   32                // chunks per scan segment
#define NSEG  (CCH / SEG)       // 16 segments
#define BETA  1.0f
#define CPB   8                 // contrib-partial blocks (2048 events each)

__device__ __forceinline__ float softplus_f(float x){
  float e = __expf(-fabsf(x));
  return fmaxf(x, 0.0f) + __logf(1.0f + e);
}

// float -> bf16 (RNE); inputs are finite non-negative here.
__device__ __forceinline__ unsigned short f2bf(float f){
  unsigned b = __float_as_uint(f);
  return (unsigned short)((b + 0x7FFFu + ((b >> 16) & 1u)) >> 16);
}
__device__ __forceinline__ float bf2f(unsigned short u){
  return __uint_as_float(((unsigned)u) << 16);
}

// T_max arrives as a 1-element array; decode int-vs-float defensively.
__device__ __forceinline__ float decode_T(const void* p){
  unsigned bits = *(const unsigned*)p;
  float fv = __uint_as_float(bits);
  return (fv >= 1e-3f && fv <= 1e7f) ? fv : (float)(int)bits;
}

__device__ __forceinline__ float wave_red(float v){
  #pragma unroll
  for (int o = 32; o > 0; o >>= 1) v += __shfl_down(v, o);
  return v;
}

// k_prep (82 blocks, nothing pre-zeroed):
//   [0,8)   : muw = softplus(log_mu)+eps ; per-block mu partial -> acc[8+b]
//   [8,72)  : 256 events = 8 chunks/block. Zero 64KB LDS tile, LDS-atomic
//             scatter SL contributions, stream tile to global (coalesced).
//   [72,80) : contrib partials: 2048 events/block scattered into 8KB LDS
//             (LDS atomics), written non-atomic to Cpart[b-72][2048].
//   [80,82) : dchunk/cumdec per chunk; Aseg (block 80); acc[0..7]=0 (block 81).
__global__ __launch_bounds__(256) void k_prep(
    const float* __restrict__ t, const int* __restrict__ m,
    const float* __restrict__ log_mu, const void* Tp,
    float* __restrict__ muw, float* __restrict__ SL,
    float* __restrict__ dchunk, float* __restrict__ cumdec,
    float* __restrict__ Aseg, float* __restrict__ Cpart,
    float* __restrict__ acc)
{
  __shared__ float Srow[8 * D_DIM];     // 64 KB
  const int b = blockIdx.x, tid = threadIdx.x;
  if (b < 8){
    int j = b*256 + tid;
    float v = softplus_f(log_mu[j]) + 1e-6f;
    muw[j] = v;
    float s = wave_red(v);
    if ((tid & 63) == 0) Srow[tid >> 6] = s;
    __syncthreads();
    if (tid == 0) acc[8 + b] = (Srow[0]+Srow[1]) + (Srow[2]+Srow[3]);
  } else if (b < 72){
    float4* S4 = (float4*)Srow;
    const float4 z = make_float4(0.f,0.f,0.f,0.f);
    #pragma unroll
    for (int k = 0; k < 16; ++k) S4[k*256 + tid] = z;
    __syncthreads();
    const int i = (b-8)*256 + tid;
    const int c = i >> 5;                       // global chunk of this event
    if (c < CCH - 1){                           // last chunk's carry unused
      float tn = t[(c+1)*LCH];
      atomicAdd(&Srow[(tid >> 5)*D_DIM + m[i]], __expf(-BETA * (tn - t[i])));
    }
    __syncthreads();
    float4* G4 = (float4*)(SL + (size_t)(b-8) * (8*D_DIM));
    #pragma unroll
    for (int k = 0; k < 16; ++k) G4[k*256 + tid] = S4[k*256 + tid];
  } else if (b < 72 + CPB){
    // contrib partial for events [(b-72)*2048, +2048)
    float* Cl = Srow;                           // first 8 KB of LDS
    float4* Cl4 = (float4*)Cl;
    const float4 z = make_float4(0.f,0.f,0.f,0.f);
    Cl4[tid*2] = z; Cl4[tid*2 + 1] = z;
    __syncthreads();
    const float T = decode_T(Tp);
    #pragma unroll
    for (int k = 0; k < 8; ++k){
      int i = (b-72)*2048 + k*256 + tid;
      atomicAdd(&Cl[m[i]], 1.0f - __expf(-BETA * (T - t[i])));
    }
    __syncthreads();
    float4* Cp4 = (float4*)(Cpart + (size_t)(b-72) * D_DIM);
    Cp4[tid*2]     = Cl4[tid*2];
    Cp4[tid*2 + 1] = Cl4[tid*2 + 1];
  } else {
    int c = (b-80)*256 + tid;                   // c in [0,512)
    float tc = t[c*LCH];
    dchunk[c] = (c < CCH-1) ? __expf(-BETA * (t[(c+1)*LCH] - tc)) : 1.0f;
    int s0c = (c >> 5) << 5;                    // segment-start chunk
    cumdec[c] = __expf(-BETA * (tc - t[s0c*LCH]));
    if (b == 80 && tid < NSEG){
      int s = tid;
      Aseg[s] = (s < NSEG-1)
        ? __expf(-BETA * (t[(s+1)*SEG*LCH] - t[s*SEG*LCH])) : 1.0f;
    }
    if (b == 81 && tid < 8) acc[tid] = 0.f;     // loglik, integral, -, ticket
  }
}

// k_scan_alpha: blocks [0,128) = per-segment local exclusive scan of SL
// (in-place, carry-out per segment); blocks [128,640) = sA =
// bf16(softplus(log_alpha)) + integral dot with contrib (Cpart-summed),
// wave-reduced to ONE atomicAdd per block (acc[1]).
__global__ __launch_bounds__(256) void k_scan_alpha(
    float* __restrict__ SL, const float* __restrict__ dchunk,
    float* __restrict__ Carry, const float* __restrict__ la,
    const float* __restrict__ Cpart, unsigned short* __restrict__ sA,
    float* __restrict__ acc)
{
  const int b = blockIdx.x, tid = threadIdx.x;
  if (b < 128){
    const int seg = b >> 3, jb = b & 7;
    const int j = jb*256 + tid;
    const int c0 = seg * SEG;
    const size_t base = (size_t)c0 * D_DIM + j;
    float u = 0.f;
    float cur[4], nxt[4];
    #pragma unroll
    for (int q = 0; q < 4; ++q) cur[q] = SL[base + (size_t)q * D_DIM];
    for (int g = 0; g < SEG; g += 4){
      #pragma unroll
      for (int q = 0; q < 4; ++q)
        nxt[q] = (g+4 < SEG) ? SL[base + (size_t)(g+4+q) * D_DIM] : 0.f;
      #pragma unroll
      for (int q = 0; q < 4; ++q){
        int c = c0 + g + q;
        float l = cur[q];
        SL[(size_t)c * D_DIM + j] = u;
        u = fmaf(dchunk[c], u, l);
      }
      #pragma unroll
      for (int q = 0; q < 4; ++q) cur[q] = nxt[q];
    }
    Carry[(size_t)seg * D_DIM + j] = u;
    return;
  }
  const int nthreads = 512*256;               // alpha-range threads
  int atid = (b-128)*256 + tid;
  // this thread's fixed column-quad: sum the 8 contrib partials (L2-resident)
  const float4* Cp4 = (const float4*)Cpart;
  const int cq = atid & 511;                  // (atid*4 mod 2048)/4
  float4 cb = make_float4(0.f,0.f,0.f,0.f);
  #pragma unroll
  for (int r = 0; r < CPB; ++r){
    float4 v = Cp4[r*512 + cq];
    cb.x += v.x; cb.y += v.y; cb.z += v.z; cb.w += v.w;
  }
  const float4* la4 = (const float4*)la;
  ushort4* sA4 = (ushort4*)sA;
  float p = 0.f;
  #pragma unroll
  for (int u = 0; u < 8; ++u){
    int i4 = atid + u * nthreads;             // stride ≡ 0 mod row -> same cols
    float4 x = la4[i4];
    float4 sp;
    sp.x = softplus_f(x.x); sp.y = softplus_f(x.y);
    sp.z = softplus_f(x.z); sp.w = softplus_f(x.w);
    ushort4 h;
    h.x = f2bf(sp.x); h.y = f2bf(sp.y); h.z = f2bf(sp.z); h.w = f2bf(sp.w);
    sA4[i4] = h;
    p = fmaf(sp.x, cb.x, p);
    p = fmaf(sp.y, cb.y, p);
    p = fmaf(sp.z, cb.z, p);
    p = fmaf(sp.w, cb.w, p);
  }
  __shared__ float red[4];
  float w = wave_red(p);
  int lane = tid & 63, wid = tid >> 6;
  if (lane == 0) red[wid] = w;
  __syncthreads();
  if (tid == 0) atomicAdd(&acc[1], red[0]+red[1]+red[2]+red[3]);
}

// k_events: one block (512 thr = 8 waves) per chunk. Decomposed (no seq S):
//   lam_k = mu[d_k] + e^{-(t_k-t0)} * (sA[d_k] . S0)
//                   + sum_{i<k} e^{-(t_k-t_i)} * sA[d_k][m_i]
// E[seg] folded on the fly from Carry/Aseg (backward weights).
__global__ __launch_bounds__(512) void k_events(
    const float* __restrict__ t, const int* __restrict__ m,
    const unsigned short* __restrict__ sA, const float* __restrict__ muw,
    const float* __restrict__ SL, const float* __restrict__ Carry,
    const float* __restrict__ Aseg, const float* __restrict__ cumdec,
    float* __restrict__ acc, const void* Tp, float* __restrict__ out){
  __shared__ float S0[D_DIM];
  __shared__ float tl[LCH];
  __shared__ int   ml[LCH];
  __shared__ float wred[8];
  const int tid = threadIdx.x;          // 0..511
  const int c = blockIdx.x;
  const int seg = c >> 5;
  const float cd = cumdec[c];

  {
    const float4 sv = *(const float4*)(SL + (size_t)c * D_DIM + tid*4);
    float4 e = {0.f, 0.f, 0.f, 0.f};
    float wgt = 1.f;
    for (int s = seg - 1; s >= 0; --s){
      const float4 cr = *(const float4*)(Carry + (size_t)s * D_DIM + tid*4);
      e.x = fmaf(cr.x, wgt, e.x); e.y = fmaf(cr.y, wgt, e.y);
      e.z = fmaf(cr.z, wgt, e.z); e.w = fmaf(cr.w, wgt, e.w);
      wgt *= Aseg[s];
    }
    float4 s;
    s.x = fmaf(e.x, cd, sv.x); s.y = fmaf(e.y, cd, sv.y);
    s.z = fmaf(e.z, cd, sv.z); s.w = fmaf(e.w, cd, sv.w);
    *(float4*)&S0[tid*4] = s;
  }
  if (tid < LCH){
    ml[tid] = m[c*LCH + tid];
    tl[tid] = t[c*LCH + tid];
  }
  __syncthreads();

  const int l = tid & 63, w = tid >> 6;
  const int l4 = l * 4;

  // lane's 32 S0 columns -> registers (one-time)
  float4 s0[8];
  #pragma unroll
  for (int u = 0; u < 8; ++u) s0[u] = *(const float4*)&S0[u*256 + l4];

  const float t0 = tl[0];
  float lgw = 0.f;
  #pragma unroll
  for (int q = 0; q < 4; ++q){
    const int k = w*4 + q;
    const int d = ml[k];
    const unsigned short* row = sA + (size_t)d * D_DIM;
    float p = 0.f;
    #pragma unroll
    for (int u = 0; u < 8; ++u){
      ushort4 a = *(const ushort4*)(row + u*256 + l4);
      p = fmaf(bf2f(a.x), s0[u].x, p);
      p = fmaf(bf2f(a.y), s0[u].y, p);
      p = fmaf(bf2f(a.z), s0[u].z, p);
      p = fmaf(bf2f(a.w), s0[u].w, p);
    }
    const float tk = tl[k];
    float g = 0.f;
    if (l < k) g = bf2f(row[ml[l]]) * __expf(tl[l] - tk);  // exact pair term
    p = fmaf(p, __expf(t0 - tk), g);
    float v = wave_red(p);
    if (l == 0) lgw += __logf(muw[d] + v + 1e-8f);
  }
  if (l == 0) wred[w] = lgw;
  __syncthreads();
  if (tid == 0){
    float lg = ((wred[0]+wred[1])+(wred[2]+wred[3]))
             + ((wred[4]+wred[5])+(wred[6]+wred[7]));
    atomicAdd(&acc[0], lg);
    __threadfence();                        // publish before taking ticket
    unsigned old = atomicAdd((unsigned*)&acc[3], 1u);
    if (old == CCH - 1){                    // last block: finalize
      float a0 = atomicAdd(&acc[0], 0.0f);  // device-scope reads
      float a1 = atomicAdd(&acc[1], 0.0f);
      float musum = 0.f;
      #pragma unroll
      for (int j = 8; j < 16; ++j) musum += atomicAdd(&acc[j], 0.0f);
      float T = decode_T(Tp);
      out[0] = a0 - (T * musum + a1 * (1.0f / BETA));
    }
  }
}

extern "C" void kernel_launch(void* const* d_in, const int* in_sizes, int n_in,
                              void* d_out, int out_size, void* d_ws, size_t ws_size,
                              hipStream_t stream) {
  const float* t_events  = (const float*)d_in[0];
  const int*   marks     = (const int*)  d_in[1];
  const void*  Tp        =               d_in[2];
  const float* log_mu    = (const float*)d_in[3];
  const float* log_alpha = (const float*)d_in[4];
  float* out = (float*)d_out;

  // ws layout (floats) — nothing requires pre-zeroing:
  // SL[CCH*D] | Carry[NSEG*D] | muw[D] | dchunk[CCH] | cumdec[CCH]
  //   | Aseg[NSEG] | Cpart[CPB*D] | acc[16] | sA[D*D bf16]
  float* ws      = (float*)d_ws;
  float* SL      = ws;
  float* Carry   = SL + (size_t)CCH * D_DIM;
  float* muw     = Carry + (size_t)NSEG * D_DIM;
  float* dchunk  = muw + D_DIM;
  float* cumdec  = dchunk + CCH;
  float* Aseg    = cumdec + CCH;
  float* Cpart   = Aseg + NSEG;
  float* acc     = Cpart + (size_t)CPB * D_DIM;
  unsigned short* sA = (unsigned short*)(acc + 16);   // 16B-aligned offset

  k_prep      <<<82, 256, 0, stream>>>(t_events, marks, log_mu, Tp, muw, SL,
                                       dchunk, cumdec, Aseg, Cpart, acc);
  k_scan_alpha<<<640, 256, 0, stream>>>(SL, dchunk, Carry, log_alpha, Cpart,
                                        sA, acc);
  k_events    <<<CCH, 512, 0, stream>>>(t_events, marks, sA, muw, SL, Carry,
                                        Aseg, cumdec, acc, Tp, out);
}